// Round 1
// baseline (1195.898 us; speedup 1.0000x reference)
//
#include <hip/hip_runtime.h>
#include <math.h>

constexpr int BATCH = 8;
constexpr int SEQ   = 1024;
constexpr int EMB   = 768;
constexpr int NHEAD = 12;
constexpr int HDIM  = 64;

// ---------------------------------------------------------------------------
// fp32 GEMM core: C = A @ W^T + bias
// A: [8192, 768] row-major, W: [768, 768] row-major.
// 128x128 tile, BK=16, 256 threads, 8x8 per thread.
// LDS tiles stored K-outer (transposed) so inner-loop reads are float4
// ds_read_b128 with broadcast (conflict-free for A, <=4-way for W).
// ---------------------------------------------------------------------------
template<bool HEAD_LAYOUT>
__device__ __forceinline__ void gemm_core(
    const float* __restrict__ A, const float* __restrict__ W,
    const float* __restrict__ bias, float* __restrict__ C)
{
    __shared__ float As[16 * 128];
    __shared__ float Ws[16 * 128];

    const int tid = threadIdx.x;
    const int tr  = tid >> 4;        // 0..15 -> rows 8*tr..8*tr+7
    const int tc  = tid & 15;        // 0..15 -> cols 8*tc..8*tc+7
    const int m0  = blockIdx.y * 128;
    const int n0  = blockIdx.x * 128;
    const int lr  = tid >> 2;        // 0..63 (load row)
    const int lk  = (tid & 3) * 4;   // 0,4,8,12 (load k chunk)

    float acc[8][8];
#pragma unroll
    for (int i = 0; i < 8; ++i)
#pragma unroll
        for (int j = 0; j < 8; ++j) acc[i][j] = 0.0f;

    const float* Ap0 = A + (size_t)(m0 + lr) * EMB + lk;
    const float* Ap1 = Ap0 + (size_t)64 * EMB;
    const float* Wp0 = W + (size_t)(n0 + lr) * EMB + lk;
    const float* Wp1 = Wp0 + (size_t)64 * EMB;

    for (int k0 = 0; k0 < EMB; k0 += 16) {
        const float4 a0 = *(const float4*)(Ap0 + k0);
        const float4 a1 = *(const float4*)(Ap1 + k0);
        const float4 w0 = *(const float4*)(Wp0 + k0);
        const float4 w1 = *(const float4*)(Wp1 + k0);
        __syncthreads();   // previous inner-loop reads complete
        As[(lk + 0) * 128 + lr]      = a0.x;
        As[(lk + 1) * 128 + lr]      = a0.y;
        As[(lk + 2) * 128 + lr]      = a0.z;
        As[(lk + 3) * 128 + lr]      = a0.w;
        As[(lk + 0) * 128 + lr + 64] = a1.x;
        As[(lk + 1) * 128 + lr + 64] = a1.y;
        As[(lk + 2) * 128 + lr + 64] = a1.z;
        As[(lk + 3) * 128 + lr + 64] = a1.w;
        Ws[(lk + 0) * 128 + lr]      = w0.x;
        Ws[(lk + 1) * 128 + lr]      = w0.y;
        Ws[(lk + 2) * 128 + lr]      = w0.z;
        Ws[(lk + 3) * 128 + lr]      = w0.w;
        Ws[(lk + 0) * 128 + lr + 64] = w1.x;
        Ws[(lk + 1) * 128 + lr + 64] = w1.y;
        Ws[(lk + 2) * 128 + lr + 64] = w1.z;
        Ws[(lk + 3) * 128 + lr + 64] = w1.w;
        __syncthreads();
#pragma unroll
        for (int k = 0; k < 16; ++k) {
            const float4 av0 = *(const float4*)&As[k * 128 + 8 * tr];
            const float4 av1 = *(const float4*)&As[k * 128 + 8 * tr + 4];
            const float4 wv0 = *(const float4*)&Ws[k * 128 + 8 * tc];
            const float4 wv1 = *(const float4*)&Ws[k * 128 + 8 * tc + 4];
            const float a[8] = {av0.x, av0.y, av0.z, av0.w,
                                av1.x, av1.y, av1.z, av1.w};
            const float w[8] = {wv0.x, wv0.y, wv0.z, wv0.w,
                                wv1.x, wv1.y, wv1.z, wv1.w};
#pragma unroll
            for (int i = 0; i < 8; ++i)
#pragma unroll
                for (int j = 0; j < 8; ++j)
                    acc[i][j] = fmaf(a[i], w[j], acc[i][j]);
        }
    }

#pragma unroll
    for (int i = 0; i < 8; ++i) {
        const int row = m0 + 8 * tr + i;
#pragma unroll
        for (int jj = 0; jj < 2; ++jj) {
            const int col = n0 + 8 * tc + 4 * jj;
            const float4 bv = *(const float4*)&bias[col];
            float4 v;
            v.x = acc[i][4 * jj + 0] + bv.x;
            v.y = acc[i][4 * jj + 1] + bv.y;
            v.z = acc[i][4 * jj + 2] + bv.z;
            v.w = acc[i][4 * jj + 3] + bv.w;
            if (HEAD_LAYOUT) {
                const int b  = row >> 10;          // row / SEQ
                const int n  = row & (SEQ - 1);
                const int h  = col >> 6;           // col / HDIM
                const int hd = col & (HDIM - 1);
                *(float4*)&C[(((size_t)(b * NHEAD + h)) * SEQ + n) * HDIM + hd] = v;
            } else {
                *(float4*)&C[(size_t)row * EMB + col] = v;
            }
        }
    }
}

__global__ __launch_bounds__(256, 2)
void gemm_qkv(const float* __restrict__ x,
              const float* __restrict__ Wq, const float* __restrict__ Wk,
              const float* __restrict__ Wv,
              const float* __restrict__ bq, const float* __restrict__ bk,
              const float* __restrict__ bv,
              float* __restrict__ Qo, float* __restrict__ Ko,
              float* __restrict__ Vo)
{
    const float* W  = (blockIdx.z == 0) ? Wq : (blockIdx.z == 1) ? Wk : Wv;
    const float* bb = (blockIdx.z == 0) ? bq : (blockIdx.z == 1) ? bk : bv;
    float*       C  = (blockIdx.z == 0) ? Qo : (blockIdx.z == 1) ? Ko : Vo;
    gemm_core<true>(x, W, bb, C);
}

__global__ __launch_bounds__(256, 2)
void gemm_out(const float* __restrict__ attn, const float* __restrict__ Wo,
              const float* __restrict__ bo, float* __restrict__ out)
{
    gemm_core<false>(attn, Wo, bo, out);
}

// ---------------------------------------------------------------------------
// Flash attention: one block per (b, h, 64-row Q tile). fp32.
// Q,K,V in [B*H, SEQ, HDIM]. Online softmax; row state (m,l) replicated
// across the 16 lanes sharing each row group (shfl-xor width-16 reductions).
// ---------------------------------------------------------------------------
__global__ __launch_bounds__(256, 2)
void flash_attn(const float* __restrict__ Q, const float* __restrict__ K,
                const float* __restrict__ V, float* __restrict__ O)
{
    __shared__ float Qt[64 * 64];   // [hd][n]  transposed
    __shared__ float Kt[64 * 64];   // [hd][m]  transposed
    __shared__ float Vs[64 * 64];   // [m][hd]
    __shared__ float Ps[64 * 68];   // [n][m]   padded stride 68

    const int tid = threadIdx.x;
    const int tr  = tid >> 4;       // 0..15 -> rows 4*tr..4*tr+3
    const int tc  = tid & 15;       // 0..15 -> cols 4*tc..4*tc+3
    const int q0  = blockIdx.x * 64;
    const int bh  = blockIdx.y;     // 0..95
    const float scale = 0.036084391824351615f;   // 768^-0.5

    const float* Qb = Q + (size_t)bh * SEQ * HDIM;
    const float* Kb = K + (size_t)bh * SEQ * HDIM;
    const float* Vb = V + (size_t)bh * SEQ * HDIM;

    const int lrow = tid >> 4;        // 0..15
    const int lcol = (tid & 15) * 4;  // 0..60

    // stage Q tile transposed
#pragma unroll
    for (int p = 0; p < 4; ++p) {
        const int row = lrow + 16 * p;
        const float4 q = *(const float4*)&Qb[(size_t)(q0 + row) * HDIM + lcol];
        Qt[(lcol + 0) * 64 + row] = q.x;
        Qt[(lcol + 1) * 64 + row] = q.y;
        Qt[(lcol + 2) * 64 + row] = q.z;
        Qt[(lcol + 3) * 64 + row] = q.w;
    }

    float m_i[4], l_i[4], acc[4][4];
#pragma unroll
    for (int i = 0; i < 4; ++i) {
        m_i[i] = -INFINITY;
        l_i[i] = 0.0f;
#pragma unroll
        for (int j = 0; j < 4; ++j) acc[i][j] = 0.0f;
    }

    for (int t0 = 0; t0 < SEQ; t0 += 64) {
        // prefetch K/V tiles to registers
        float4 kpre[4], vpre[4];
#pragma unroll
        for (int p = 0; p < 4; ++p) {
            const int row = lrow + 16 * p;
            kpre[p] = *(const float4*)&Kb[(size_t)(t0 + row) * HDIM + lcol];
            vpre[p] = *(const float4*)&Vb[(size_t)(t0 + row) * HDIM + lcol];
        }
        __syncthreads();   // previous iteration's PV reads done
#pragma unroll
        for (int p = 0; p < 4; ++p) {
            const int row = lrow + 16 * p;
            Kt[(lcol + 0) * 64 + row] = kpre[p].x;
            Kt[(lcol + 1) * 64 + row] = kpre[p].y;
            Kt[(lcol + 2) * 64 + row] = kpre[p].z;
            Kt[(lcol + 3) * 64 + row] = kpre[p].w;
            *(float4*)&Vs[row * 64 + lcol] = vpre[p];
        }
        __syncthreads();

        // S = scale * (Q K^T) for this tile
        float s[4][4];
#pragma unroll
        for (int i = 0; i < 4; ++i)
#pragma unroll
            for (int j = 0; j < 4; ++j) s[i][j] = 0.0f;
#pragma unroll
        for (int k = 0; k < 64; ++k) {
            const float4 qv = *(const float4*)&Qt[k * 64 + 4 * tr];
            const float4 kv = *(const float4*)&Kt[k * 64 + 4 * tc];
            const float qa[4] = {qv.x, qv.y, qv.z, qv.w};
            const float ka[4] = {kv.x, kv.y, kv.z, kv.w};
#pragma unroll
            for (int i = 0; i < 4; ++i)
#pragma unroll
                for (int j = 0; j < 4; ++j)
                    s[i][j] = fmaf(qa[i], ka[j], s[i][j]);
        }

        // online softmax (per-row state replicated over the 16 lanes of a row)
        float pp[4][4];
#pragma unroll
        for (int i = 0; i < 4; ++i) {
            float tmax = -INFINITY;
#pragma unroll
            for (int j = 0; j < 4; ++j) {
                s[i][j] *= scale;
                tmax = fmaxf(tmax, s[i][j]);
            }
#pragma unroll
            for (int off = 8; off >= 1; off >>= 1)
                tmax = fmaxf(tmax, __shfl_xor(tmax, off));
            const float mnew  = fmaxf(m_i[i], tmax);
            const float alpha = __expf(m_i[i] - mnew);
            float rsum = 0.0f;
#pragma unroll
            for (int j = 0; j < 4; ++j) {
                pp[i][j] = __expf(s[i][j] - mnew);
                rsum += pp[i][j];
            }
#pragma unroll
            for (int off = 8; off >= 1; off >>= 1)
                rsum += __shfl_xor(rsum, off);
            l_i[i] = l_i[i] * alpha + rsum;
            m_i[i] = mnew;
#pragma unroll
            for (int j = 0; j < 4; ++j) acc[i][j] *= alpha;
        }

        // P -> LDS
#pragma unroll
        for (int i = 0; i < 4; ++i)
#pragma unroll
            for (int j = 0; j < 4; ++j)
                Ps[(4 * tr + i) * 68 + 4 * tc + j] = pp[i][j];
        __syncthreads();

        // O += P V
#pragma unroll
        for (int mm = 0; mm < 64; mm += 4) {
            float pr[4][4], vr[4][4];
#pragma unroll
            for (int i = 0; i < 4; ++i) {
                const float4 t = *(const float4*)&Ps[(4 * tr + i) * 68 + mm];
                pr[i][0] = t.x; pr[i][1] = t.y; pr[i][2] = t.z; pr[i][3] = t.w;
            }
#pragma unroll
            for (int u = 0; u < 4; ++u) {
                const float4 t = *(const float4*)&Vs[(mm + u) * 64 + 4 * tc];
                vr[u][0] = t.x; vr[u][1] = t.y; vr[u][2] = t.z; vr[u][3] = t.w;
            }
#pragma unroll
            for (int i = 0; i < 4; ++i)
#pragma unroll
                for (int u = 0; u < 4; ++u)
#pragma unroll
                    for (int j = 0; j < 4; ++j)
                        acc[i][j] = fmaf(pr[i][u], vr[u][j], acc[i][j]);
        }
    }

    // epilogue: divide by l, write [B, N, D] with head offset
    const int b = bh / NHEAD;
    const int h = bh % NHEAD;
#pragma unroll
    for (int i = 0; i < 4; ++i) {
        const float inv = 1.0f / l_i[i];
        const int n = q0 + 4 * tr + i;
        float4 v;
        v.x = acc[i][0] * inv;
        v.y = acc[i][1] * inv;
        v.z = acc[i][2] * inv;
        v.w = acc[i][3] * inv;
        *(float4*)&O[((size_t)(b * SEQ + n)) * EMB + h * HDIM + 4 * tc] = v;
    }
}

extern "C" void kernel_launch(void* const* d_in, const int* in_sizes, int n_in,
                              void* d_out, int out_size, void* d_ws, size_t ws_size,
                              hipStream_t stream)
{
    const float* x  = (const float*)d_in[0];
    const float* Wq = (const float*)d_in[1];
    const float* bq = (const float*)d_in[2];
    const float* Wk = (const float*)d_in[3];
    const float* bk = (const float*)d_in[4];
    const float* Wv = (const float*)d_in[5];
    const float* bv = (const float*)d_in[6];
    const float* Wo = (const float*)d_in[7];
    const float* bo = (const float*)d_in[8];
    float* out = (float*)d_out;

    const size_t per = (size_t)BATCH * SEQ * EMB;   // 6,291,456 floats
    float* Qb   = (float*)d_ws;
    float* Kb   = Qb + per;
    float* Vb   = Kb + per;
    float* attn = Vb + per;   // total 4*per floats = 96 MiB

    // QKV projections (fused across grid.z), head-major outputs
    gemm_qkv<<<dim3(EMB / 128, (BATCH * SEQ) / 128, 3), 256, 0, stream>>>(
        x, Wq, Wk, Wv, bq, bk, bv, Qb, Kb, Vb);

    // flash attention
    flash_attn<<<dim3(SEQ / 64, BATCH * NHEAD), 256, 0, stream>>>(Qb, Kb, Vb, attn);

    // output projection
    gemm_out<<<dim3(EMB / 128, (BATCH * SEQ) / 128), 256, 0, stream>>>(attn, Wo, bo, out);
}

// Round 2
// 370.099 us; speedup vs baseline: 3.2313x; 3.2313x over previous
//
#include <hip/hip_runtime.h>
#include <math.h>

// Round 2: full bf16-MFMA rewrite.
//   cast_all:  x + 4 weights fp32 -> bf16 (once per call, ~10 us)
//   gemm_qkv:  [8192x768]x[768x768]^T x3 via 16x16x32 bf16 MFMA, m97-style
//              global_load_lds staging; epilogue scatters Q,K head-major and
//              V transposed ([bh][hd][n]) so flash needs no V transpose.
//   flash_bf16: barrier-free waves; Q/K/V frags straight from global
//              (coalesced permuted-dense pattern), P via wave-private LDS.
//   gemm_outp: same GEMM core, fp32 output + bias.

typedef __bf16 bf16x8 __attribute__((ext_vector_type(8)));
typedef float  f32x4  __attribute__((ext_vector_type(4)));
typedef unsigned short ushort_t;

__device__ __forceinline__ unsigned short f2bf(float f) {
    unsigned u = __float_as_uint(f);
    u += 0x7fffu + ((u >> 16) & 1u);          // round-to-nearest-even
    return (unsigned short)(u >> 16);
}
__device__ __forceinline__ float bf2f(unsigned short h) {
    return __uint_as_float(((unsigned)h) << 16);
}

#define GLL16(g, l)                                                                        \
    __builtin_amdgcn_global_load_lds((const __attribute__((address_space(1))) void*)(g),   \
                                     (__attribute__((address_space(3))) void*)(l), 16, 0, 0)

// ---------------------------------------------------------------------------
// cast fp32 -> bf16: y=0 -> x (6.29M), y=1..4 -> Wq,Wk,Wv,Wo (589824 each)
// ---------------------------------------------------------------------------
__global__ __launch_bounds__(256)
void cast_all(const float* __restrict__ x,
              const float* __restrict__ w0, const float* __restrict__ w1,
              const float* __restrict__ w2, const float* __restrict__ w3,
              ushort_t* __restrict__ xb, ushort_t* __restrict__ wb0,
              ushort_t* __restrict__ wb1, ushort_t* __restrict__ wb2,
              ushort_t* __restrict__ wb3)
{
    const int y = blockIdx.y;
    const float* s; ushort_t* d; int n;
    switch (y) {
        case 0:  s = x;  d = xb;  n = 8192 * 768; break;
        case 1:  s = w0; d = wb0; n = 768 * 768;  break;
        case 2:  s = w1; d = wb1; n = 768 * 768;  break;
        case 3:  s = w2; d = wb2; n = 768 * 768;  break;
        default: s = w3; d = wb3; n = 768 * 768;  break;
    }
    const int i = (blockIdx.x * 256 + threadIdx.x) * 8;
    if (i >= n) return;
    const float4 f0 = *(const float4*)(s + i);
    const float4 f1 = *(const float4*)(s + i + 4);
    ushort4 p0, p1;
    p0.x = f2bf(f0.x); p0.y = f2bf(f0.y); p0.z = f2bf(f0.z); p0.w = f2bf(f0.w);
    p1.x = f2bf(f1.x); p1.y = f2bf(f1.y); p1.z = f2bf(f1.z); p1.w = f2bf(f1.w);
    *(ushort4*)(d + i)     = p0;
    *(ushort4*)(d + i + 4) = p1;
}

// ---------------------------------------------------------------------------
// GEMM core: C128x128 = A[8192x768] . W[768x768]^T, bf16 MFMA 16x16x32.
// 256 thr = 4 waves in 2x2; each wave 64x64 (acc[4][4] of f32x4).
// LDS tiles 128x32 bf16 row-major, filled by global_load_lds width 16.
// ---------------------------------------------------------------------------
__device__ __forceinline__ void gemm_core_mfma(
    const ushort_t* __restrict__ A, const ushort_t* __restrict__ W,
    int m0, int n0, f32x4 acc[4][4])
{
    __shared__ ushort_t As[128 * 32];
    __shared__ ushort_t Ws[128 * 32];
    const int tid = threadIdx.x;
    const int L   = tid & 63;
    const int wv  = tid >> 6;
    const int wr  = wv >> 1, wc = wv & 1;
    const int c   = L & 15,  g  = L >> 4;

    const int c0 = tid, c1 = tid + 256;
    const ushort_t* a0 = A + (size_t)(m0 + (c0 >> 2)) * 768 + (c0 & 3) * 8;
    const ushort_t* a1 = A + (size_t)(m0 + (c1 >> 2)) * 768 + (c1 & 3) * 8;
    const ushort_t* w0 = W + (size_t)(n0 + (c0 >> 2)) * 768 + (c0 & 3) * 8;
    const ushort_t* w1 = W + (size_t)(n0 + (c1 >> 2)) * 768 + (c1 & 3) * 8;

#pragma unroll
    for (int i = 0; i < 4; ++i)
#pragma unroll
        for (int j = 0; j < 4; ++j) acc[i][j] = (f32x4){0.f, 0.f, 0.f, 0.f};

    for (int k0 = 0; k0 < 768; k0 += 32) {
        __syncthreads();                       // prior ds_reads complete
        GLL16(a0 + k0, &As[(size_t)c0 * 8]);
        GLL16(a1 + k0, &As[(size_t)c1 * 8]);
        GLL16(w0 + k0, &Ws[(size_t)c0 * 8]);
        GLL16(w1 + k0, &Ws[(size_t)c1 * 8]);
        __syncthreads();                       // staging visible
        bf16x8 af[4], bfr[4];
#pragma unroll
        for (int i = 0; i < 4; ++i)
            af[i] = *(const bf16x8*)&As[(wr * 64 + i * 16 + c) * 32 + g * 8];
#pragma unroll
        for (int j = 0; j < 4; ++j)
            bfr[j] = *(const bf16x8*)&Ws[(wc * 64 + j * 16 + c) * 32 + g * 8];
#pragma unroll
        for (int i = 0; i < 4; ++i)
#pragma unroll
            for (int j = 0; j < 4; ++j)
                acc[i][j] = __builtin_amdgcn_mfma_f32_16x16x32_bf16(
                    af[i], bfr[j], acc[i][j], 0, 0, 0);
    }
}

// QKV: z=0 Q, z=1 K -> [bh][n][64]; z=2 V -> transposed [bh][hd][1024]
__global__ __launch_bounds__(256, 2)
void gemm_qkv(const ushort_t* __restrict__ xb,
              const ushort_t* __restrict__ wqb, const ushort_t* __restrict__ wkb,
              const ushort_t* __restrict__ wvb,
              const float* __restrict__ bq, const float* __restrict__ bk,
              const float* __restrict__ bv,
              ushort_t* __restrict__ Qh, ushort_t* __restrict__ Kh,
              ushort_t* __restrict__ Vt)
{
    const int z = blockIdx.z;
    const ushort_t* W   = (z == 0) ? wqb : (z == 1) ? wkb : wvb;
    const float*    bia = (z == 0) ? bq  : (z == 1) ? bk  : bv;
    const int m0 = blockIdx.y * 128, n0 = blockIdx.x * 128;
    f32x4 acc[4][4];
    gemm_core_mfma(xb, W, m0, n0, acc);

    const int tid = threadIdx.x, L = tid & 63, wv2 = tid >> 6;
    const int wr = wv2 >> 1, wc = wv2 & 1, c = L & 15, g = L >> 4;
#pragma unroll
    for (int i = 0; i < 4; ++i) {
        const int row0 = m0 + wr * 64 + i * 16 + g * 4;   // +r, all same batch
        const int b = row0 >> 10;
        const int n = row0 & 1023;
#pragma unroll
        for (int j = 0; j < 4; ++j) {
            const int col = n0 + wc * 64 + j * 16 + c;
            const int h = col >> 6, hd = col & 63;
            const float bsv = bia[col];
            if (z < 2) {
                ushort_t* dst = ((z == 0) ? Qh : Kh)
                              + ((size_t)((b * 12 + h) * 1024 + n)) * 64 + hd;
#pragma unroll
                for (int r = 0; r < 4; ++r)
                    dst[(size_t)r * 64] = f2bf(acc[i][j][r] + bsv);
            } else {
                ushort4 pk;
                pk.x = f2bf(acc[i][j][0] + bsv);
                pk.y = f2bf(acc[i][j][1] + bsv);
                pk.z = f2bf(acc[i][j][2] + bsv);
                pk.w = f2bf(acc[i][j][3] + bsv);
                *(ushort4*)&Vt[((size_t)((b * 12 + h) * 64 + hd)) * 1024 + n] = pk;
            }
        }
    }
}

__global__ __launch_bounds__(256, 2)
void gemm_outp(const ushort_t* __restrict__ attnb, const ushort_t* __restrict__ wob,
               const float* __restrict__ bo, float* __restrict__ out)
{
    const int m0 = blockIdx.y * 128, n0 = blockIdx.x * 128;
    f32x4 acc[4][4];
    gemm_core_mfma(attnb, wob, m0, n0, acc);
    const int tid = threadIdx.x, L = tid & 63, wv2 = tid >> 6;
    const int wr = wv2 >> 1, wc = wv2 & 1, c = L & 15, g = L >> 4;
#pragma unroll
    for (int i = 0; i < 4; ++i) {
        const int row = m0 + wr * 64 + i * 16 + g * 4;
#pragma unroll
        for (int j = 0; j < 4; ++j) {
            const int col = n0 + wc * 64 + j * 16 + c;
            const float bsv = bo[col];
#pragma unroll
            for (int r = 0; r < 4; ++r)
                out[(size_t)(row + r) * 768 + col] = acc[i][j][r] + bsv;
        }
    }
}

// ---------------------------------------------------------------------------
// Flash attention, bf16 MFMA, barrier-free (P strip is wave-private LDS).
// Q,K: [bh][n][64] bf16; Vt: [bh][hd][1024] bf16. Out: attn bf16 [8192][768].
// Block: (64 Q rows, one bh); 4 waves x 16 rows. K-tiles of 64, 16 iters.
// ---------------------------------------------------------------------------
__global__ __launch_bounds__(256)
void flash_bf16(const ushort_t* __restrict__ Q, const ushort_t* __restrict__ K,
                const ushort_t* __restrict__ Vt, ushort_t* __restrict__ attnb)
{
    __shared__ ushort_t Ps[4][16 * 72];        // per-wave P strip, stride 72
    const int tid = threadIdx.x;
    const int wv = tid >> 6, L = tid & 63, c = L & 15, g = L >> 4;
    const int bh = blockIdx.y, q0 = blockIdx.x * 64;
    const float SC2 = 0.05205954985329743f;    // 768^-0.5 * log2(e)

    const ushort_t* Qp = Q + ((size_t)bh * 1024 + q0 + wv * 16 + c) * 64 + g * 8;
    const bf16x8 qf0 = *(const bf16x8*)Qp;
    const bf16x8 qf1 = *(const bf16x8*)(Qp + 32);

    f32x4 o[4];
    float m_i[4], l_i[4], alpha[4];
#pragma unroll
    for (int ht = 0; ht < 4; ++ht) o[ht] = (f32x4){0.f, 0.f, 0.f, 0.f};
#pragma unroll
    for (int r = 0; r < 4; ++r) { m_i[r] = -INFINITY; l_i[r] = 0.f; }

    ushort_t* myPs = &Ps[wv][0];
    const ushort_t* Kp = K + ((size_t)bh * 1024 + c) * 64 + g * 8;
    const ushort_t* Vp = Vt + ((size_t)bh * 64 + c) * 1024 + g * 8;

    for (int t0 = 0; t0 < 1024; t0 += 64) {
        // V frags (independent of S chain -> issue early)
        bf16x8 vf[4][2];
#pragma unroll
        for (int ht = 0; ht < 4; ++ht) {
            const ushort_t* vp = Vp + (size_t)ht * 16 * 1024 + t0;
            vf[ht][0] = *(const bf16x8*)vp;
            vf[ht][1] = *(const bf16x8*)(vp + 32);
        }
        // S = Q K^T (raw, scale folded into exp2)
        f32x4 s[4];
#pragma unroll
        for (int ct = 0; ct < 4; ++ct) {
            const ushort_t* kp = Kp + ((size_t)t0 + ct * 16) * 64;
            const bf16x8 k0 = *(const bf16x8*)kp;
            const bf16x8 k1 = *(const bf16x8*)(kp + 32);
            f32x4 z = (f32x4){0.f, 0.f, 0.f, 0.f};
            z = __builtin_amdgcn_mfma_f32_16x16x32_bf16(qf0, k0, z, 0, 0, 0);
            z = __builtin_amdgcn_mfma_f32_16x16x32_bf16(qf1, k1, z, 0, 0, 0);
            s[ct] = z;
        }
        // online softmax per row r (rows live in quads; shfl<=8 stays in-quad)
        unsigned short pb[4][4];               // [ct][r]
#pragma unroll
        for (int r = 0; r < 4; ++r) {
            float mx = fmaxf(fmaxf(s[0][r], s[1][r]), fmaxf(s[2][r], s[3][r]));
            mx = fmaxf(mx, __shfl_xor(mx, 1));
            mx = fmaxf(mx, __shfl_xor(mx, 2));
            mx = fmaxf(mx, __shfl_xor(mx, 4));
            mx = fmaxf(mx, __shfl_xor(mx, 8));
            mx *= SC2;
            const float mnew = fmaxf(m_i[r], mx);
            alpha[r] = exp2f(m_i[r] - mnew);
            float ls = 0.f;
#pragma unroll
            for (int ct = 0; ct < 4; ++ct) {
                const float p = exp2f(fmaf(s[ct][r], SC2, -mnew));
                const unsigned short pv = f2bf(p);
                pb[ct][r] = pv;
                ls += bf2f(pv);                // sum rounded values for exact avg
            }
            ls += __shfl_xor(ls, 1);
            ls += __shfl_xor(ls, 2);
            ls += __shfl_xor(ls, 4);
            ls += __shfl_xor(ls, 8);
            l_i[r] = l_i[r] * alpha[r] + ls;
            m_i[r] = mnew;
        }
#pragma unroll
        for (int ht = 0; ht < 4; ++ht)
#pragma unroll
            for (int r = 0; r < 4; ++r) o[ht][r] *= alpha[r];

        // P -> wave-private LDS, pair-packed b32 (even lane ct{0,1}, odd {2,3})
        unsigned a01[4], a23[4], b01[4], b23[4];
#pragma unroll
        for (int ct = 0; ct < 4; ++ct) {
            a01[ct] = (unsigned)pb[ct][0] | ((unsigned)pb[ct][1] << 16);
            a23[ct] = (unsigned)pb[ct][2] | ((unsigned)pb[ct][3] << 16);
            b01[ct] = __shfl_xor(a01[ct], 1);
            b23[ct] = __shfl_xor(a23[ct], 1);
        }
        const int odd = c & 1, ce = c & ~1;
#pragma unroll
        for (int q = 0; q < 2; ++q) {
            const int ct = odd * 2 + q;
            const unsigned lo01 = odd ? b01[ct] : a01[ct];
            const unsigned hi01 = odd ? a01[ct] : b01[ct];
            const unsigned lo23 = odd ? b23[ct] : a23[ct];
            const unsigned hi23 = odd ? a23[ct] : b23[ct];
#pragma unroll
            for (int r = 0; r < 4; ++r) {
                const unsigned lo = (r < 2) ? lo01 : lo23;
                const unsigned hi = (r < 2) ? hi01 : hi23;
                const unsigned sh = 16u * (r & 1);
                const unsigned wrd = ((lo >> sh) & 0xffffu) | (((hi >> sh) & 0xffffu) << 16);
                *(unsigned*)&myPs[(g * 4 + r) * 72 + ct * 16 + ce] = wrd;
            }
        }
        // O += P V   (A-frag = own strip rows; same-wave LDS RAW, no barrier)
        const bf16x8 pf0 = *(const bf16x8*)&myPs[c * 72 + g * 8];
        const bf16x8 pf1 = *(const bf16x8*)&myPs[c * 72 + 32 + g * 8];
#pragma unroll
        for (int ht = 0; ht < 4; ++ht) {
            o[ht] = __builtin_amdgcn_mfma_f32_16x16x32_bf16(pf0, vf[ht][0], o[ht], 0, 0, 0);
            o[ht] = __builtin_amdgcn_mfma_f32_16x16x32_bf16(pf1, vf[ht][1], o[ht], 0, 0, 0);
        }
    }

    // epilogue: normalize, write bf16 [token][feature]
    const int b = bh / 12, h = bh % 12;
#pragma unroll
    for (int r = 0; r < 4; ++r) {
        const float inv = 1.f / l_i[r];
        const int n = q0 + wv * 16 + g * 4 + r;
        ushort_t* dst = attnb + ((size_t)b * 1024 + n) * 768 + h * 64 + c;
#pragma unroll
        for (int ht = 0; ht < 4; ++ht)
            dst[ht * 16] = f2bf(o[ht][r] * inv);
    }
}

extern "C" void kernel_launch(void* const* d_in, const int* in_sizes, int n_in,
                              void* d_out, int out_size, void* d_ws, size_t ws_size,
                              hipStream_t stream)
{
    const float* x  = (const float*)d_in[0];
    const float* Wq = (const float*)d_in[1];
    const float* bq = (const float*)d_in[2];
    const float* Wk = (const float*)d_in[3];
    const float* bk = (const float*)d_in[4];
    const float* Wv = (const float*)d_in[5];
    const float* bv = (const float*)d_in[6];
    const float* Wo = (const float*)d_in[7];
    const float* bo = (const float*)d_in[8];
    float* out = (float*)d_out;

    char* ws = (char*)d_ws;
    ushort_t* xb    = (ushort_t*)(ws);                         // 12,582,912 B
    ushort_t* wqb   = (ushort_t*)(ws + 12582912);              //  1,179,648 B
    ushort_t* wkb   = (ushort_t*)(ws + 12582912 + 1179648);
    ushort_t* wvb   = (ushort_t*)(ws + 12582912 + 2359296);
    ushort_t* wob   = (ushort_t*)(ws + 12582912 + 3538944);
    ushort_t* Qh    = (ushort_t*)(ws + 17301504);              // 12,582,912 B
    ushort_t* Kh    = (ushort_t*)(ws + 29884416);
    ushort_t* Vt    = (ushort_t*)(ws + 42467328);
    ushort_t* attnb = (ushort_t*)(ws + 55050240);              // end 67,633,152

    cast_all<<<dim3(3072, 5), 256, 0, stream>>>(x, Wq, Wk, Wv, Wo,
                                                xb, wqb, wkb, wvb, wob);
    gemm_qkv<<<dim3(6, 64, 3), 256, 0, stream>>>(xb, wqb, wkb, wvb,
                                                 bq, bk, bv, Qh, Kh, Vt);
    flash_bf16<<<dim3(16, 96), 256, 0, stream>>>(Qh, Kh, Vt, attnb);
    gemm_outp<<<dim3(6, 64), 256, 0, stream>>>(attnb, wob, bo, out);
}